// Round 5
// baseline (2722.539 us; speedup 1.0000x reference)
//
#include <hip/hip_runtime.h>
#include <hip/hip_bf16.h>
#include <math.h>

// LSTM: S=512, B=64, I=1024, H=1024
// out[S,B,H] fp32, then h_last[B,H], c_last[B,H]
//
//  1) convert x,W_ih,W_hh -> bf16 in ws
//  2) gates_x[S*B,4H] = x @ W_ih^T  (128x128 MFMA GEMM, bf16 out)
//  3) ONE persistent cooperative kernel runs all 512 steps.
//     R8: 8 rings x 8 batches x 32 col-blocks (32 cols each), grid=256,
//     1 block/CU. Each ring pinned to ONE XCD via runtime discovery
//     (s_getreg XCC_ID + atomic claim + grid rendezvous). When the claim
//     is even (32 blocks/XCD), ALL ring communication stays inside that
//     XCD's shared L2: plain stores publish h (write-through L1->L2),
//     flags polled with WORKGROUP-SCOPE ATOMIC CAS (atomics always execute
//     in L2 -- architecturally L1-proof, unlike R7's sc0 load which could
//     spin on a stale L1 line = the R7 hang), plain cached loads gather h
//     (fresh addresses each step -> never in any L1/L2 before the
//     producers' write-through). Every handoff hop drops from LLC latency
//     (~500-900cy) to L2 (~150-300cy). If the claim is uneven, fall back
//     to the R6-proven sc1/LLC protocol with bid-based rings.

#define S_LEN 512
#define BATCH 64
#define IDIM 1024
#define HDIM 1024
#define GDIM 4096
#define MAGIC 0x1337BEEFu
#define HSLOT (BATCH * HDIM)   // 65536 ushorts = 128 KiB per ring slot
#define NRING 8
#define RB 8                   // batches per ring
#define NBLK 32                // col-blocks per ring
#define CPB 32                 // h-cols per block

typedef __bf16 bf16x8 __attribute__((ext_vector_type(8)));
typedef float f32x4 __attribute__((ext_vector_type(4)));

__device__ inline ushort f2b(float f) {
    union { float f; unsigned u; } v; v.f = f;
    unsigned u = v.u;
    unsigned r = (u + 0x7fffu + ((u >> 16) & 1u)) >> 16;
    return (ushort)r;
}
__device__ inline float b2f(ushort u) {
    union { unsigned u; float f; } v; v.u = ((unsigned)u) << 16;
    return v.f;
}
__device__ inline float sigmoidf_(float x) { return 1.f / (1.f + __expf(-x)); }
__device__ inline float tanhf_(float x) {
    return 1.f - 2.f / (__expf(2.f * x) + 1.f);
}

// ---------- conversion kernels ----------
__global__ __launch_bounds__(256) void f2b_kernel(ushort* __restrict__ dst,
                                                  const float* __restrict__ src, int n) {
    int i = (blockIdx.x * 256 + threadIdx.x) * 4;
    if (i < n) {
        float4 v = *(const float4*)(src + i);
        ushort4 o;
        o.x = f2b(v.x); o.y = f2b(v.y); o.z = f2b(v.z); o.w = f2b(v.w);
        *(ushort4*)(dst + i) = o;
    }
}

__global__ __launch_bounds__(256) void bias_kernel(float* __restrict__ bias,
                                                   const float* __restrict__ b_ih,
                                                   const float* __restrict__ b_hh) {
    int i = blockIdx.x * 256 + threadIdx.x;
    if (i < GDIM) bias[i] = b_ih[i] + b_hh[i];
}

// ---------- big GEMM: C[M,N] = A[M,K] @ B[N,K]^T ----------
#define LDSS 72
__global__ __launch_bounds__(256) void gemm_bt_kernel(const ushort* __restrict__ A,
                                                      const ushort* __restrict__ B,
                                                      ushort* __restrict__ C,
                                                      int M, int N, int K) {
    __shared__ __align__(16) ushort As[128 * LDSS];
    __shared__ __align__(16) ushort Bs[128 * LDSS];
    const int tid = threadIdx.x;
    const int lane = tid & 63;
    const int wave = tid >> 6;
    const int l15 = lane & 15;
    const int quad = lane >> 4;
    const int bn = blockIdx.x;
    const int bm = blockIdx.y;
    const int wrow = (wave & 1) * 64;
    const int wcol = (wave >> 1) * 64;

    f32x4 acc[4][4] = {};

    for (int kt = 0; kt < K; kt += 64) {
        #pragma unroll
        for (int i = 0; i < 4; i++) {
            int chunk = tid + i * 256;
            int r = chunk >> 3;
            int c8 = (chunk & 7) * 8;
            *(uint4*)&As[r * LDSS + c8] =
                *(const uint4*)&A[(size_t)(bm * 128 + r) * K + kt + c8];
            *(uint4*)&Bs[r * LDSS + c8] =
                *(const uint4*)&B[(size_t)(bn * 128 + r) * K + kt + c8];
        }
        __syncthreads();
        #pragma unroll
        for (int kc = 0; kc < 2; kc++) {
            const int ko = kc * 32 + quad * 8;
            bf16x8 af[4], bf[4];
            #pragma unroll
            for (int m = 0; m < 4; m++)
                af[m] = *(const bf16x8*)&As[(wrow + m * 16 + l15) * LDSS + ko];
            #pragma unroll
            for (int n = 0; n < 4; n++)
                bf[n] = *(const bf16x8*)&Bs[(wcol + n * 16 + l15) * LDSS + ko];
            #pragma unroll
            for (int m = 0; m < 4; m++)
                #pragma unroll
                for (int n = 0; n < 4; n++)
                    acc[m][n] = __builtin_amdgcn_mfma_f32_16x16x32_bf16(af[m], bf[n], acc[m][n], 0, 0, 0);
        }
        __syncthreads();
    }
    const int col0 = bn * 128 + wcol;
    const int row0 = bm * 128 + wrow;
    #pragma unroll
    for (int m = 0; m < 4; m++) {
        #pragma unroll
        for (int n = 0; n < 4; n++) {
            int col = col0 + n * 16 + l15;
            int rbase = row0 + m * 16 + quad * 4;
            #pragma unroll
            for (int r = 0; r < 4; r++)
                C[(size_t)(rbase + r) * N + col] = f2b(acc[m][n][r]);
        }
    }
}

// ---------- persistent recurrence kernel ----------
// Grid = 256 blocks = 8 rings x 32 col-blocks. Ring r owns batches
// [r*8, r*8+8); col-block pos owns h-cols [pos*32, pos*32+32).
// 512 threads = 8 waves: wave wv -> gate = wv&3, khalf = wv>>2.
// Each wave: 16(8 valid batches)x32 output tile over K=512 via 2 col-frag
// chains; partials summed in LDS. W_hh b-frags in regs: 32 x bf16x8 = 128.
#define HS2 1032        // Hs row stride in elems (R0-proven conflict floor)
#define GS_CS 33        // Gs col stride +1 pad (floats per row)

__global__ __launch_bounds__(512, 2) void lstm_persistent(
    const ushort* __restrict__ gx,
    ushort* __restrict__ hring,
    const ushort* __restrict__ Whh,
    const float* __restrict__ bias,
    const float* __restrict__ c0,
    float* __restrict__ out,
    unsigned* __restrict__ flags,
    unsigned* __restrict__ claim)   // claim[0..7] per-XCD counters, claim[8] done
{
    __shared__ __align__(16) ushort Hs[16 * HS2];          // 33,024 B (rows 8..15 zero)
    __shared__ float Gs[2 * 4 * 16 * GS_CS];               // 16,896 B
    __shared__ int sh_ring, sh_pos, sh_ok;

    const int tid = threadIdx.x;
    const int lane = tid & 63;
    const int wv = tid >> 6;
    const int gate = wv & 3;
    const int kh = wv >> 2;
    const int l15 = lane & 15;
    const int quad = lane >> 4;
    const int bid = blockIdx.x;

    // ---- XCD discovery + ring claim + grid rendezvous ----
    if (tid == 0) {
        unsigned xcd;
        asm volatile("s_getreg_b32 %0, hwreg(HW_REG_XCC_ID)" : "=s"(xcd));
        xcd &= 7;
        int p = (int)__hip_atomic_fetch_add(&claim[xcd], 1u, __ATOMIC_RELAXED,
                                            __HIP_MEMORY_SCOPE_AGENT);
        __hip_atomic_fetch_add(&claim[8], 1u, __ATOMIC_RELEASE,
                               __HIP_MEMORY_SCOPE_AGENT);
        while (__hip_atomic_load(&claim[8], __ATOMIC_RELAXED,
                                 __HIP_MEMORY_SCOPE_AGENT) < NRING * NBLK)
            __builtin_amdgcn_s_sleep(8);
        int ok = 1;
        #pragma unroll
        for (int i = 0; i < 8; i++)
            ok &= (__hip_atomic_load(&claim[i], __ATOMIC_RELAXED,
                                     __HIP_MEMORY_SCOPE_AGENT) == NBLK);
        sh_ring = ok ? (int)xcd : (bid & 7);
        sh_pos  = ok ? p : (bid >> 3);
        sh_ok = ok;
    }
    // zero Hs rows 8..15 (read by MFMA for nonexistent batches, discarded)
    for (int i = tid; i < 8 * HS2; i += 512) Hs[8 * HS2 + i] = 0;
    __syncthreads();
    const int ring = sh_ring;
    const int pos = sh_pos;
    const bool l2ok = (sh_ok != 0);

    // ---- preload W fragments: rows gate*1024 + pos*32 + cg*16 + l15 ----
    bf16x8 wf[2][16];
    {
        #pragma unroll
        for (int cg = 0; cg < 2; cg++) {
            const ushort* wrow = Whh
                + ((size_t)(gate * 1024 + pos * CPB + cg * 16 + l15)) * 1024
                + kh * 512 + quad * 8;
            #pragma unroll
            for (int ks = 0; ks < 16; ks++)
                wf[cg][ks] = *(const bf16x8*)(wrow + ks * 32);
        }
    }

    // ---- pointwise per-thread state: threads 0..127 own (pb, pj), (pb, pj+1) ----
    const bool pw = (tid < 128);
    const int pb = tid >> 4;            // local batch 0..7 (when pw)
    const int pj = (tid & 15) * 2;      // col pair 0..30
    const int gb = ring * RB + pb;      // global batch
    const int pcol = pos * CPB + pj;
    float2 creg = {0.f, 0.f};
    if (pw) creg = *(const float2*)&c0[(size_t)gb * HDIM + pcol];
    float bsum[4][2];
    #pragma unroll
    for (int g = 0; g < 4; g++) {
        bsum[g][0] = bias[g * 1024 + pcol];
        bsum[g][1] = bias[g * 1024 + pcol + 1];
    }
    const size_t gx_tb = (size_t)gb * GDIM + pcol;

    #pragma unroll 1
    for (int s = 0; s < S_LEN; s++) {
        const ushort* hsrc = hring + (size_t)s * HSLOT + (size_t)ring * RB * HDIM;

        // prefetch gx[s] (independent of h) before the flag wait
        ushort2 gxr[4] = {};
        if (pw) {
            const ushort* gxs = gx + (size_t)s * BATCH * GDIM + gx_tb;
            #pragma unroll
            for (int g = 0; g < 4; g++)
                gxr[g] = *(const ushort2*)(gxs + g * 1024);
        }

        // wait for this ring's h_s: wave0 polls the ring's 32 flags.
        if (s > 0) {
            if (wv == 0) {
                unsigned* fp = flags + ((size_t)s * NRING + ring) * NBLK + (lane & 31);
                if (l2ok) {
                    // L2-executed atomic CAS: architecturally bypasses L1.
                    // CAS(MAGIC->MAGIC) is benign; returns old value in exp.
                    while (true) {
                        unsigned exp = MAGIC;
                        if (lane < 32)
                            __hip_atomic_compare_exchange_strong(
                                fp, &exp, MAGIC, __ATOMIC_RELAXED,
                                __ATOMIC_RELAXED, __HIP_MEMORY_SCOPE_WORKGROUP);
                        if (__ballot(exp != MAGIC) == 0ull) break;
                        __builtin_amdgcn_s_sleep(1);
                    }
                } else {
                    while (true) {
                        unsigned v = __hip_atomic_load(fp, __ATOMIC_RELAXED,
                                                       __HIP_MEMORY_SCOPE_AGENT);
                        if (__ballot(v != MAGIC) == 0ull) break;
                        __builtin_amdgcn_s_sleep(2);
                    }
                }
            }
            __syncthreads();   // releases all waves; fences h loads below poll
        }

        // gather ring's h slice (8x1024 bf16 = 16 KiB), stage into LDS.
        if (l2ok) {
            // plain cached loads: fresh addresses (never touched by this CU
            // before); producers share this XCD's L2 -> coherent.
            const uint4* h128 = (const uint4*)hsrc;
            uint4 hr[2];
            #pragma unroll
            for (int c = 0; c < 2; c++)
                hr[c] = h128[c * 512 + tid];
            #pragma unroll
            for (int c = 0; c < 2; c++) {
                int u = c * 512 + tid;
                int row = u >> 7;             // 128 uint4 per 1024-col row
                int col = (u & 127) * 8;
                *(uint4*)&Hs[row * HS2 + col] = hr[c];
            }
        } else {
            const unsigned long long* h64 = (const unsigned long long*)hsrc;
            unsigned long long hr[4];
            #pragma unroll
            for (int c = 0; c < 4; c++)
                hr[c] = __hip_atomic_load(&h64[c * 512 + tid], __ATOMIC_RELAXED,
                                          __HIP_MEMORY_SCOPE_AGENT);
            #pragma unroll
            for (int c = 0; c < 4; c++) {
                int u = c * 512 + tid;
                int row = u >> 8;             // 256 x 8B per 1024-col row
                int col = (u & 255) * 4;
                *(unsigned long long*)&Hs[row * HS2 + col] = hr[c];
            }
        }
        __syncthreads();

        // MFMA: wave (gate, kh) computes 16(8 valid)x32 over K=512
        f32x4 acc[2] = {};
        const int arow = l15 * HS2 + kh * 512 + quad * 8;
        #pragma unroll
        for (int ks = 0; ks < 16; ks++) {
            bf16x8 a = *(const bf16x8*)&Hs[arow + ks * 32];
            acc[0] = __builtin_amdgcn_mfma_f32_16x16x32_bf16(a, wf[0][ks], acc[0], 0, 0, 0);
            acc[1] = __builtin_amdgcn_mfma_f32_16x16x32_bf16(a, wf[1][ks], acc[1], 0, 0, 0);
        }

        // exchange partial gates through LDS (C layout: col=l15, row=quad*4+r)
        #pragma unroll
        for (int cg = 0; cg < 2; cg++)
            #pragma unroll
            for (int r = 0; r < 4; r++)
                Gs[((kh * 4 + gate) * 16 + quad * 4 + r) * GS_CS + cg * 16 + l15] = acc[cg][r];
        __syncthreads();

        // pointwise: threads 0..127, 2 elements each (sum the 2 K-partials)
        float hv[2], cv[2];
        if (pw) {
            #pragma unroll
            for (int u = 0; u < 2; u++) {
                float cold = u ? creg.y : creg.x;
                float g0 = Gs[((0 * 4 + 0) * 16 + pb) * GS_CS + pj + u]
                         + Gs[((1 * 4 + 0) * 16 + pb) * GS_CS + pj + u]
                         + bsum[0][u] + b2f(u ? gxr[0].y : gxr[0].x);
                float g1 = Gs[((0 * 4 + 1) * 16 + pb) * GS_CS + pj + u]
                         + Gs[((1 * 4 + 1) * 16 + pb) * GS_CS + pj + u]
                         + bsum[1][u] + b2f(u ? gxr[1].y : gxr[1].x);
                float g2 = Gs[((0 * 4 + 2) * 16 + pb) * GS_CS + pj + u]
                         + Gs[((1 * 4 + 2) * 16 + pb) * GS_CS + pj + u]
                         + bsum[2][u] + b2f(u ? gxr[2].y : gxr[2].x);
                float g3 = Gs[((0 * 4 + 3) * 16 + pb) * GS_CS + pj + u]
                         + Gs[((1 * 4 + 3) * 16 + pb) * GS_CS + pj + u]
                         + bsum[3][u] + b2f(u ? gxr[3].y : gxr[3].x);
                float ig = sigmoidf_(g0);
                float fg = sigmoidf_(g1);
                float gg = tanhf_(g2);
                float og = sigmoidf_(g3);
                float cn = fg * cold + ig * gg;
                float hn = og * tanhf_(cn);
                cv[u] = cn; hv[u] = hn;
            }
            creg.x = cv[0]; creg.y = cv[1];

            // publish h_{s+1} into the NEXT ring slot (4B packed bf16x2).
            if (s < S_LEN - 1) {
                unsigned* hd = (unsigned*)(hring + (size_t)(s + 1) * HSLOT
                                           + (size_t)gb * HDIM + pcol);
                unsigned hword = (unsigned)f2b(hv[0]) | ((unsigned)f2b(hv[1]) << 16);
                if (l2ok) {
                    *hd = hword;               // plain: write-through L1 -> shared L2
                } else {
                    __hip_atomic_store(hd, hword, __ATOMIC_RELAXED,
                                       __HIP_MEMORY_SCOPE_AGENT);
                }
            }
        }

        // barrier drains each wave's vmcnt: all h stores acked at their
        // coherence point (L2 in path A, LLC in path B) before the flag.
        __syncthreads();
        if (tid == 0 && s < S_LEN - 1) {
            asm volatile("s_waitcnt vmcnt(0)" ::: "memory");
            unsigned* fd = flags + ((size_t)(s + 1) * NRING + ring) * NBLK + pos;
            if (l2ok) {
                *fd = MAGIC;                   // plain store -> shared L2
            } else {
                __hip_atomic_store(fd, MAGIC, __ATOMIC_RELAXED,
                                   __HIP_MEMORY_SCOPE_AGENT);
            }
        }

        // out store AFTER the flag publish (off the handoff path).
        if (pw) {
            float2 ho; ho.x = hv[0]; ho.y = hv[1];
            *(float2*)&out[(size_t)s * BATCH * HDIM + (size_t)gb * HDIM + pcol] = ho;
            if (s == S_LEN - 1) {
                float* tail = out + (size_t)S_LEN * BATCH * HDIM;
                *(float2*)&tail[(size_t)gb * HDIM + pcol] = ho;
                float2 co; co.x = cv[0]; co.y = cv[1];
                *(float2*)&tail[BATCH * HDIM + (size_t)gb * HDIM + pcol] = co;
            }
        }
    }
}

extern "C" void kernel_launch(void* const* d_in, const int* in_sizes, int n_in,
                              void* d_out, int out_size, void* d_ws, size_t ws_size,
                              hipStream_t stream) {
    const float* x    = (const float*)d_in[0];
    const float* h0   = (const float*)d_in[1];
    const float* c0   = (const float*)d_in[2];
    const float* W_ih = (const float*)d_in[3];
    const float* b_ih = (const float*)d_in[4];
    const float* W_hh = (const float*)d_in[5];
    const float* b_hh = (const float*)d_in[6];
    float* out = (float*)d_out;

    const size_t n_x  = (size_t)S_LEN * BATCH * IDIM;
    const size_t n_w  = (size_t)GDIM * IDIM;
    // xb (64 MiB) doubles as the h ring: 512 slots x 128 KiB, reused only
    // after the GEMM has consumed x.
    const size_t o_xb    = 0;
    const size_t o_gx    = o_xb + n_x * 2;
    const size_t o_wih   = o_gx + (size_t)S_LEN * BATCH * GDIM * 2;
    const size_t o_whh   = o_wih + n_w * 2;
    const size_t o_bias  = o_whh + n_w * 2;
    const size_t o_flags = o_bias + GDIM * 4;
    const size_t flags_bytes = (size_t)(S_LEN + 1) * NRING * NBLK * 4;
    const size_t o_claim = o_flags + flags_bytes;
    const size_t claim_bytes = 64;
    const size_t total  = o_claim + claim_bytes;
    if (ws_size < total) return;

    char* ws = (char*)d_ws;
    ushort* xb   = (ushort*)(ws + o_xb);
    ushort* hring = xb;                       // ring overlays xb
    ushort* gx   = (ushort*)(ws + o_gx);
    ushort* wihb = (ushort*)(ws + o_wih);
    ushort* whhb = (ushort*)(ws + o_whh);
    float*  bias = (float*)(ws + o_bias);
    unsigned* flags = (unsigned*)(ws + o_flags);
    unsigned* claim = (unsigned*)(ws + o_claim);

    // conversions + bias + flag/claim reset
    f2b_kernel<<<(int)(n_x / 1024), 256, 0, stream>>>(xb, x, (int)n_x);
    f2b_kernel<<<(int)(n_w / 1024), 256, 0, stream>>>(wihb, W_ih, (int)n_w);
    f2b_kernel<<<(int)(n_w / 1024), 256, 0, stream>>>(whhb, W_hh, (int)n_w);
    bias_kernel<<<GDIM / 256, 256, 0, stream>>>(bias, b_ih, b_hh);
    hipMemsetAsync(flags, 0, flags_bytes + claim_bytes, stream);

    // gates_x = x @ W_ih^T  (M=32768, N=4096, K=1024)
    {
        dim3 grid(GDIM / 128, (S_LEN * BATCH) / 128);
        gemm_bt_kernel<<<grid, 256, 0, stream>>>(xb, wihb, gx, S_LEN * BATCH, GDIM, IDIM);
    }

    // h0 -> ring slot 0 (AFTER the GEMM: it overwrites the head of xb)
    f2b_kernel<<<(BATCH * HDIM) / 1024, 256, 0, stream>>>(hring, h0, BATCH * HDIM);

    // persistent recurrence (cooperative: all 256 blocks co-resident)
    {
        const ushort* gx_c = gx;
        const ushort* whh_c = whhb;
        const float* bias_c = bias;
        void* args[] = { (void*)&gx_c, (void*)&hring, (void*)&whh_c,
                         (void*)&bias_c, (void*)&c0, (void*)&out, (void*)&flags,
                         (void*)&claim };
        hipLaunchCooperativeKernel((const void*)lstm_persistent, dim3(NRING * NBLK), dim3(512),
                                   args, 0, stream);
    }
}

// Round 6
// 2437.410 us; speedup vs baseline: 1.1170x; 1.1170x over previous
//
#include <hip/hip_runtime.h>
#include <hip/hip_bf16.h>
#include <math.h>

// LSTM: S=512, B=64, I=1024, H=1024
// out[S,B,H] fp32, then h_last[B,H], c_last[B,H]
//
//  1) convert x,W_ih,W_hh -> bf16 in ws
//  2) gates_x[S*B,4H] = x @ W_ih^T  (128x128 MFMA GEMM, bf16 out)
//  3) ONE persistent cooperative kernel runs all 512 steps.
//     R9: 8 rings x 8 batches x 32 col-blocks (32 cols each), grid=256,
//     1 block/CU, ring pinned to ONE XCD (s_getreg XCC_ID + atomic claim +
//     grid rendezvous; R8-proven: FETCH dropped 793->197 MB). All ring
//     communication stays in the XCD's shared L2: plain stores publish h,
//     plain cached loads gather it (fresh ring addresses each step).
//     Sync (new in R9): ONE per-ring step COUNTER (256B-strided lines)
//     replaces the 32-flag array. Producers fetch_add(+1) once after the
//     vmcnt drain; the consumer polls with a single-lane benign CAS(32->32)
//     -- an RMW executes at L2 (L1-proof; a plain/workgroup LOAD could spin
//     on stale L1 = the R7 hang; idempotent fetch_add(0) risks LLVM's
//     atomicrmw->load rewrite). This kills R8's CAS storm (~1024 RMW/64cy
//     on 2 lines, which queued ahead of the last flag store and stole L2
//     slots from h publish/gather). Uneven claim -> R6-proven sc1/LLC
//     fallback with agent-scope counter ops.

#define S_LEN 512
#define BATCH 64
#define IDIM 1024
#define HDIM 1024
#define GDIM 4096
#define HSLOT (BATCH * HDIM)   // 65536 ushorts = 128 KiB per ring slot
#define NRING 8
#define RB 8                   // batches per ring
#define NBLK 32                // col-blocks per ring
#define CPB 32                 // h-cols per block
#define CTR_STRIDE 64          // unsigneds per ring-step counter (256 B)

typedef __bf16 bf16x8 __attribute__((ext_vector_type(8)));
typedef float f32x4 __attribute__((ext_vector_type(4)));

__device__ inline ushort f2b(float f) {
    union { float f; unsigned u; } v; v.f = f;
    unsigned u = v.u;
    unsigned r = (u + 0x7fffu + ((u >> 16) & 1u)) >> 16;
    return (ushort)r;
}
__device__ inline float b2f(ushort u) {
    union { unsigned u; float f; } v; v.u = ((unsigned)u) << 16;
    return v.f;
}
__device__ inline float sigmoidf_(float x) { return 1.f / (1.f + __expf(-x)); }
__device__ inline float tanhf_(float x) {
    return 1.f - 2.f / (__expf(2.f * x) + 1.f);
}

// ---------- conversion kernels ----------
__global__ __launch_bounds__(256) void f2b_kernel(ushort* __restrict__ dst,
                                                  const float* __restrict__ src, int n) {
    int i = (blockIdx.x * 256 + threadIdx.x) * 4;
    if (i < n) {
        float4 v = *(const float4*)(src + i);
        ushort4 o;
        o.x = f2b(v.x); o.y = f2b(v.y); o.z = f2b(v.z); o.w = f2b(v.w);
        *(ushort4*)(dst + i) = o;
    }
}

__global__ __launch_bounds__(256) void bias_kernel(float* __restrict__ bias,
                                                   const float* __restrict__ b_ih,
                                                   const float* __restrict__ b_hh) {
    int i = blockIdx.x * 256 + threadIdx.x;
    if (i < GDIM) bias[i] = b_ih[i] + b_hh[i];
}

// ---------- big GEMM: C[M,N] = A[M,K] @ B[N,K]^T ----------
#define LDSS 72
__global__ __launch_bounds__(256) void gemm_bt_kernel(const ushort* __restrict__ A,
                                                      const ushort* __restrict__ B,
                                                      ushort* __restrict__ C,
                                                      int M, int N, int K) {
    __shared__ __align__(16) ushort As[128 * LDSS];
    __shared__ __align__(16) ushort Bs[128 * LDSS];
    const int tid = threadIdx.x;
    const int lane = tid & 63;
    const int wave = tid >> 6;
    const int l15 = lane & 15;
    const int quad = lane >> 4;
    const int bn = blockIdx.x;
    const int bm = blockIdx.y;
    const int wrow = (wave & 1) * 64;
    const int wcol = (wave >> 1) * 64;

    f32x4 acc[4][4] = {};

    for (int kt = 0; kt < K; kt += 64) {
        #pragma unroll
        for (int i = 0; i < 4; i++) {
            int chunk = tid + i * 256;
            int r = chunk >> 3;
            int c8 = (chunk & 7) * 8;
            *(uint4*)&As[r * LDSS + c8] =
                *(const uint4*)&A[(size_t)(bm * 128 + r) * K + kt + c8];
            *(uint4*)&Bs[r * LDSS + c8] =
                *(const uint4*)&B[(size_t)(bn * 128 + r) * K + kt + c8];
        }
        __syncthreads();
        #pragma unroll
        for (int kc = 0; kc < 2; kc++) {
            const int ko = kc * 32 + quad * 8;
            bf16x8 af[4], bf[4];
            #pragma unroll
            for (int m = 0; m < 4; m++)
                af[m] = *(const bf16x8*)&As[(wrow + m * 16 + l15) * LDSS + ko];
            #pragma unroll
            for (int n = 0; n < 4; n++)
                bf[n] = *(const bf16x8*)&Bs[(wcol + n * 16 + l15) * LDSS + ko];
            #pragma unroll
            for (int m = 0; m < 4; m++)
                #pragma unroll
                for (int n = 0; n < 4; n++)
                    acc[m][n] = __builtin_amdgcn_mfma_f32_16x16x32_bf16(af[m], bf[n], acc[m][n], 0, 0, 0);
        }
        __syncthreads();
    }
    const int col0 = bn * 128 + wcol;
    const int row0 = bm * 128 + wrow;
    #pragma unroll
    for (int m = 0; m < 4; m++) {
        #pragma unroll
        for (int n = 0; n < 4; n++) {
            int col = col0 + n * 16 + l15;
            int rbase = row0 + m * 16 + quad * 4;
            #pragma unroll
            for (int r = 0; r < 4; r++)
                C[(size_t)(rbase + r) * N + col] = f2b(acc[m][n][r]);
        }
    }
}

// ---------- persistent recurrence kernel ----------
// Grid = 256 blocks = 8 rings x 32 col-blocks. Ring r owns batches
// [r*8, r*8+8); col-block pos owns h-cols [pos*32, pos*32+32).
// 512 threads = 8 waves: wave wv -> gate = wv&3, khalf = wv>>2.
// Each wave: 16(8 valid batches)x32 output tile over K=512 via 2 col-frag
// chains; partials summed in LDS. W_hh b-frags in regs: 32 x bf16x8 = 128.
#define HS2 1032        // Hs row stride in elems (R0-proven conflict floor)
#define GS_CS 33        // Gs col stride +1 pad (floats per row)

__global__ __launch_bounds__(512, 2) void lstm_persistent(
    const ushort* __restrict__ gx,
    ushort* __restrict__ hring,
    const ushort* __restrict__ Whh,
    const float* __restrict__ bias,
    const float* __restrict__ c0,
    float* __restrict__ out,
    unsigned* __restrict__ ctr,     // (S+1) x NRING counters, 256B stride
    unsigned* __restrict__ claim)   // claim[0..7] per-XCD counters, claim[8] done
{
    __shared__ __align__(16) ushort Hs[16 * HS2];          // 33,024 B (rows 8..15 zero)
    __shared__ float Gs[2 * 4 * 16 * GS_CS];               // 16,896 B
    __shared__ int sh_ring, sh_pos, sh_ok;

    const int tid = threadIdx.x;
    const int lane = tid & 63;
    const int wv = tid >> 6;
    const int gate = wv & 3;
    const int kh = wv >> 2;
    const int l15 = lane & 15;
    const int quad = lane >> 4;
    const int bid = blockIdx.x;

    // ---- XCD discovery + ring claim + grid rendezvous ----
    if (tid == 0) {
        unsigned xcd;
        asm volatile("s_getreg_b32 %0, hwreg(HW_REG_XCC_ID)" : "=s"(xcd));
        xcd &= 7;
        int p = (int)__hip_atomic_fetch_add(&claim[xcd], 1u, __ATOMIC_RELAXED,
                                            __HIP_MEMORY_SCOPE_AGENT);
        __hip_atomic_fetch_add(&claim[8], 1u, __ATOMIC_RELEASE,
                               __HIP_MEMORY_SCOPE_AGENT);
        while (__hip_atomic_load(&claim[8], __ATOMIC_RELAXED,
                                 __HIP_MEMORY_SCOPE_AGENT) < NRING * NBLK)
            __builtin_amdgcn_s_sleep(8);
        int ok = 1;
        #pragma unroll
        for (int i = 0; i < 8; i++)
            ok &= (__hip_atomic_load(&claim[i], __ATOMIC_RELAXED,
                                     __HIP_MEMORY_SCOPE_AGENT) == NBLK);
        sh_ring = ok ? (int)xcd : (bid & 7);
        sh_pos  = ok ? p : (bid >> 3);
        sh_ok = ok;
    }
    // zero Hs rows 8..15 (read by MFMA for nonexistent batches, discarded)
    for (int i = tid; i < 8 * HS2; i += 512) Hs[8 * HS2 + i] = 0;
    __syncthreads();
    const int ring = sh_ring;
    const int pos = sh_pos;
    const bool l2ok = (sh_ok != 0);

    // ---- preload W fragments: rows gate*1024 + pos*32 + cg*16 + l15 ----
    bf16x8 wf[2][16];
    {
        #pragma unroll
        for (int cg = 0; cg < 2; cg++) {
            const ushort* wrow = Whh
                + ((size_t)(gate * 1024 + pos * CPB + cg * 16 + l15)) * 1024
                + kh * 512 + quad * 8;
            #pragma unroll
            for (int ks = 0; ks < 16; ks++)
                wf[cg][ks] = *(const bf16x8*)(wrow + ks * 32);
        }
    }

    // ---- pointwise per-thread state: threads 0..127 own (pb, pj), (pb, pj+1) ----
    const bool pw = (tid < 128);
    const int pb = tid >> 4;            // local batch 0..7 (when pw)
    const int pj = (tid & 15) * 2;      // col pair 0..30
    const int gb = ring * RB + pb;      // global batch
    const int pcol = pos * CPB + pj;
    float2 creg = {0.f, 0.f};
    if (pw) creg = *(const float2*)&c0[(size_t)gb * HDIM + pcol];
    float bsum[4][2];
    #pragma unroll
    for (int g = 0; g < 4; g++) {
        bsum[g][0] = bias[g * 1024 + pcol];
        bsum[g][1] = bias[g * 1024 + pcol + 1];
    }
    const size_t gx_tb = (size_t)gb * GDIM + pcol;

    #pragma unroll 1
    for (int s = 0; s < S_LEN; s++) {
        const ushort* hsrc = hring + (size_t)s * HSLOT + (size_t)ring * RB * HDIM;

        // prefetch gx[s] (independent of h) before the counter wait
        ushort2 gxr[4] = {};
        if (pw) {
            const ushort* gxs = gx + (size_t)s * BATCH * GDIM + gx_tb;
            #pragma unroll
            for (int g = 0; g < 4; g++)
                gxr[g] = *(const ushort2*)(gxs + g * 1024);
        }

        // wait for this ring's h_s: ONE lane polls ONE counter word.
        if (s > 0) {
            if (tid == 0) {
                unsigned* cp = ctr + ((size_t)s * NRING + ring) * CTR_STRIDE;
                if (l2ok) {
                    // benign CAS(32->32): real RMW, executes at L2 (L1-proof),
                    // writes nothing until the count is complete.
                    while (true) {
                        unsigned exp = NBLK;
                        __hip_atomic_compare_exchange_strong(
                            cp, &exp, NBLK, __ATOMIC_RELAXED,
                            __ATOMIC_RELAXED, __HIP_MEMORY_SCOPE_WORKGROUP);
                        if (exp == NBLK) break;
                        __builtin_amdgcn_s_sleep(1);
                    }
                } else {
                    // fallback: sc1 load polls the LLC-resident counter.
                    while (__hip_atomic_load(cp, __ATOMIC_RELAXED,
                                             __HIP_MEMORY_SCOPE_AGENT) != NBLK)
                        __builtin_amdgcn_s_sleep(2);
                }
            }
            __syncthreads();   // releases all waves; fences h loads below poll
        }

        // gather ring's h slice (8x1024 bf16 = 16 KiB), stage into LDS.
        if (l2ok) {
            // plain cached loads: fresh addresses (never touched by this CU
            // before); producers share this XCD's L2 -> coherent.
            const uint4* h128 = (const uint4*)hsrc;
            uint4 hr[2];
            #pragma unroll
            for (int c = 0; c < 2; c++)
                hr[c] = h128[c * 512 + tid];
            #pragma unroll
            for (int c = 0; c < 2; c++) {
                int u = c * 512 + tid;
                int row = u >> 7;             // 128 uint4 per 1024-col row
                int col = (u & 127) * 8;
                *(uint4*)&Hs[row * HS2 + col] = hr[c];
            }
        } else {
            const unsigned long long* h64 = (const unsigned long long*)hsrc;
            unsigned long long hr[4];
            #pragma unroll
            for (int c = 0; c < 4; c++)
                hr[c] = __hip_atomic_load(&h64[c * 512 + tid], __ATOMIC_RELAXED,
                                          __HIP_MEMORY_SCOPE_AGENT);
            #pragma unroll
            for (int c = 0; c < 4; c++) {
                int u = c * 512 + tid;
                int row = u >> 8;             // 256 x 8B per 1024-col row
                int col = (u & 255) * 4;
                *(unsigned long long*)&Hs[row * HS2 + col] = hr[c];
            }
        }
        __syncthreads();

        // MFMA: wave (gate, kh) computes 16(8 valid)x32 over K=512
        f32x4 acc[2] = {};
        const int arow = l15 * HS2 + kh * 512 + quad * 8;
        #pragma unroll
        for (int ks = 0; ks < 16; ks++) {
            bf16x8 a = *(const bf16x8*)&Hs[arow + ks * 32];
            acc[0] = __builtin_amdgcn_mfma_f32_16x16x32_bf16(a, wf[0][ks], acc[0], 0, 0, 0);
            acc[1] = __builtin_amdgcn_mfma_f32_16x16x32_bf16(a, wf[1][ks], acc[1], 0, 0, 0);
        }

        // exchange partial gates through LDS (C layout: col=l15, row=quad*4+r)
        #pragma unroll
        for (int cg = 0; cg < 2; cg++)
            #pragma unroll
            for (int r = 0; r < 4; r++)
                Gs[((kh * 4 + gate) * 16 + quad * 4 + r) * GS_CS + cg * 16 + l15] = acc[cg][r];
        __syncthreads();

        // pointwise: threads 0..127, 2 elements each (sum the 2 K-partials)
        float hv[2], cv[2];
        if (pw) {
            #pragma unroll
            for (int u = 0; u < 2; u++) {
                float cold = u ? creg.y : creg.x;
                float g0 = Gs[((0 * 4 + 0) * 16 + pb) * GS_CS + pj + u]
                         + Gs[((1 * 4 + 0) * 16 + pb) * GS_CS + pj + u]
                         + bsum[0][u] + b2f(u ? gxr[0].y : gxr[0].x);
                float g1 = Gs[((0 * 4 + 1) * 16 + pb) * GS_CS + pj + u]
                         + Gs[((1 * 4 + 1) * 16 + pb) * GS_CS + pj + u]
                         + bsum[1][u] + b2f(u ? gxr[1].y : gxr[1].x);
                float g2 = Gs[((0 * 4 + 2) * 16 + pb) * GS_CS + pj + u]
                         + Gs[((1 * 4 + 2) * 16 + pb) * GS_CS + pj + u]
                         + bsum[2][u] + b2f(u ? gxr[2].y : gxr[2].x);
                float g3 = Gs[((0 * 4 + 3) * 16 + pb) * GS_CS + pj + u]
                         + Gs[((1 * 4 + 3) * 16 + pb) * GS_CS + pj + u]
                         + bsum[3][u] + b2f(u ? gxr[3].y : gxr[3].x);
                float ig = sigmoidf_(g0);
                float fg = sigmoidf_(g1);
                float gg = tanhf_(g2);
                float og = sigmoidf_(g3);
                float cn = fg * cold + ig * gg;
                float hn = og * tanhf_(cn);
                cv[u] = cn; hv[u] = hn;
            }
            creg.x = cv[0]; creg.y = cv[1];

            // publish h_{s+1} into the NEXT ring slot (4B packed bf16x2).
            if (s < S_LEN - 1) {
                unsigned* hd = (unsigned*)(hring + (size_t)(s + 1) * HSLOT
                                           + (size_t)gb * HDIM + pcol);
                unsigned hword = (unsigned)f2b(hv[0]) | ((unsigned)f2b(hv[1]) << 16);
                if (l2ok) {
                    *hd = hword;               // plain: write-through L1 -> shared L2
                } else {
                    __hip_atomic_store(hd, hword, __ATOMIC_RELAXED,
                                       __HIP_MEMORY_SCOPE_AGENT);
                }
            }
        }

        // barrier drains each wave's vmcnt: all h stores acked at their
        // coherence point (L2 in path A, LLC in path B) before the inc.
        __syncthreads();
        if (tid == 0 && s < S_LEN - 1) {
            asm volatile("s_waitcnt vmcnt(0)" ::: "memory");
            unsigned* cp = ctr + ((size_t)(s + 1) * NRING + ring) * CTR_STRIDE;
            if (l2ok) {
                __hip_atomic_fetch_add(cp, 1u, __ATOMIC_RELAXED,
                                       __HIP_MEMORY_SCOPE_WORKGROUP);
            } else {
                __hip_atomic_fetch_add(cp, 1u, __ATOMIC_RELAXED,
                                       __HIP_MEMORY_SCOPE_AGENT);
            }
        }

        // out store AFTER the counter publish (off the handoff path).
        if (pw) {
            float2 ho; ho.x = hv[0]; ho.y = hv[1];
            *(float2*)&out[(size_t)s * BATCH * HDIM + (size_t)gb * HDIM + pcol] = ho;
            if (s == S_LEN - 1) {
                float* tail = out + (size_t)S_LEN * BATCH * HDIM;
                *(float2*)&tail[(size_t)gb * HDIM + pcol] = ho;
                float2 co; co.x = cv[0]; co.y = cv[1];
                *(float2*)&tail[BATCH * HDIM + (size_t)gb * HDIM + pcol] = co;
            }
        }
    }
}

extern "C" void kernel_launch(void* const* d_in, const int* in_sizes, int n_in,
                              void* d_out, int out_size, void* d_ws, size_t ws_size,
                              hipStream_t stream) {
    const float* x    = (const float*)d_in[0];
    const float* h0   = (const float*)d_in[1];
    const float* c0   = (const float*)d_in[2];
    const float* W_ih = (const float*)d_in[3];
    const float* b_ih = (const float*)d_in[4];
    const float* W_hh = (const float*)d_in[5];
    const float* b_hh = (const float*)d_in[6];
    float* out = (float*)d_out;

    const size_t n_x  = (size_t)S_LEN * BATCH * IDIM;
    const size_t n_w  = (size_t)GDIM * IDIM;
    // xb (64 MiB) doubles as the h ring: 512 slots x 128 KiB, reused only
    // after the GEMM has consumed x.
    const size_t o_xb    = 0;
    const size_t o_gx    = o_xb + n_x * 2;
    const size_t o_wih   = o_gx + (size_t)S_LEN * BATCH * GDIM * 2;
    const size_t o_whh   = o_wih + n_w * 2;
    const size_t o_bias  = o_whh + n_w * 2;
    const size_t o_ctr   = o_bias + GDIM * 4;
    const size_t ctr_bytes = (size_t)(S_LEN + 1) * NRING * CTR_STRIDE * 4;
    const size_t o_claim = o_ctr + ctr_bytes;
    const size_t claim_bytes = 64;
    const size_t total  = o_claim + claim_bytes;
    if (ws_size < total) return;

    char* ws = (char*)d_ws;
    ushort* xb   = (ushort*)(ws + o_xb);
    ushort* hring = xb;                       // ring overlays xb
    ushort* gx   = (ushort*)(ws + o_gx);
    ushort* wihb = (ushort*)(ws + o_wih);
    ushort* whhb = (ushort*)(ws + o_whh);
    float*  bias = (float*)(ws + o_bias);
    unsigned* ctr = (unsigned*)(ws + o_ctr);
    unsigned* claim = (unsigned*)(ws + o_claim);

    // conversions + bias + counter/claim reset
    f2b_kernel<<<(int)(n_x / 1024), 256, 0, stream>>>(xb, x, (int)n_x);
    f2b_kernel<<<(int)(n_w / 1024), 256, 0, stream>>>(wihb, W_ih, (int)n_w);
    f2b_kernel<<<(int)(n_w / 1024), 256, 0, stream>>>(whhb, W_hh, (int)n_w);
    bias_kernel<<<GDIM / 256, 256, 0, stream>>>(bias, b_ih, b_hh);
    hipMemsetAsync(ctr, 0, ctr_bytes + claim_bytes, stream);

    // gates_x = x @ W_ih^T  (M=32768, N=4096, K=1024)
    {
        dim3 grid(GDIM / 128, (S_LEN * BATCH) / 128);
        gemm_bt_kernel<<<grid, 256, 0, stream>>>(xb, wihb, gx, S_LEN * BATCH, GDIM, IDIM);
    }

    // h0 -> ring slot 0 (AFTER the GEMM: it overwrites the head of xb)
    f2b_kernel<<<(BATCH * HDIM) / 1024, 256, 0, stream>>>(hring, h0, BATCH * HDIM);

    // persistent recurrence (cooperative: all 256 blocks co-resident)
    {
        const ushort* gx_c = gx;
        const ushort* whh_c = whhb;
        const float* bias_c = bias;
        void* args[] = { (void*)&gx_c, (void*)&hring, (void*)&whh_c,
                         (void*)&bias_c, (void*)&c0, (void*)&out, (void*)&ctr,
                         (void*)&claim };
        hipLaunchCooperativeKernel((const void*)lstm_persistent, dim3(NRING * NBLK), dim3(512),
                                   args, 0, stream);
    }
}